// Round 4
// baseline (88.054 us; speedup 1.0000x reference)
//
#include <hip/hip_runtime.h>
#include <math.h>

// 6-qubit statevector sim, one batch element per LANE PAIR (2 threads/element),
// all complex math as VOP3P packed fp32 (v_pk_fma_f32 + op_sel/neg_lo).
//
// Round-3 post-mortem: packed fp32 runs at HALF instruction rate on gfx950
// (scalar v_fma_f32 already saturates the 157.3 TF fp32 pipe), so pk halves
// issue-slot pressure, not VALU cycles. The VALU floor (~16 us) is fixed;
// what's missing is ISSUE EFFICIENCY: at 1 elem/thread the grid gives only
// 2 waves/SIMD (2048 waves / 1024 SIMDs) -> each wave gets an issue slot
// every ~4 cyc and FMA dep latency (~4cyc) leaves ~40% utilization.
// Fix: lane-pair split (q0 <-> lane parity) -> 4096 waves = 4 waves/SIMD.
// Round-1 tried this but __launch_bounds__(256,4) capped VGPR at 64 ->
// state spilled (76 MB scratch). Here: (256,2) = 128-VGPR budget (round-2
// empirical), state is 32 float2 = 64 VGPR, peak ~110 -> no spill, and
// <=128 VGPR still admits 4 waves/SIMD.
// Cross-pair traffic (q0 gate, CNOTs touching q0) via DPP quad_perm lane^1.

// ---- packed complex primitives (validated round 3) ------------------------
// cmul: t = (gr*ar - gi*ai, gr*ai + gi*ar)
__device__ __forceinline__ float2 pk_cmul(float2 g, float2 a) {
    float2 t;
    asm("v_pk_mul_f32 %0, %1, %2 op_sel:[0,0] op_sel_hi:[0,1]"
        : "=v"(t) : "v"(g), "v"(a));
    asm("v_pk_fma_f32 %0, %1, %2, %0 op_sel:[1,1,0] op_sel_hi:[1,0,1] neg_lo:[1,0,0]"
        : "+v"(t) : "v"(g), "v"(a));
    return t;
}
// cmac: acc += g*a
__device__ __forceinline__ float2 pk_cmac(float2 acc, float2 g, float2 a) {
    asm("v_pk_fma_f32 %0, %1, %2, %0 op_sel:[0,0,0] op_sel_hi:[0,1,1]"
        : "+v"(acc) : "v"(g), "v"(a));
    asm("v_pk_fma_f32 %0, %1, %2, %0 op_sel:[1,1,0] op_sel_hi:[1,0,1] neg_lo:[1,0,0]"
        : "+v"(acc) : "v"(g), "v"(a));
    return acc;
}
// acc += a*a (elementwise)
__device__ __forceinline__ float2 pk_sqacc(float2 acc, float2 a) {
    asm("v_pk_fma_f32 %0, %1, %1, %0" : "+v"(acc) : "v"(a));
    return acc;
}
// acc += a*b (elementwise)
__device__ __forceinline__ float2 pk_macv(float2 acc, float2 a, float2 b) {
    asm("v_pk_fma_f32 %0, %1, %2, %0" : "+v"(acc) : "v"(a), "v"(b));
    return acc;
}

// lane ^ 1 exchange via DPP quad_perm [1,0,3,2] — 1 VALU instr per float.
__device__ __forceinline__ float xpair(float v) {
    return __int_as_float(__builtin_amdgcn_mov_dpp(__float_as_int(v), 0xB1, 0xF, 0xF, true));
}
__device__ __forceinline__ float2 xpair2(float2 v) {
    return make_float2(xpair(v.x), xpair(v.y));
}

// Apply 2x2 complex gate to LOCAL qubit with mask M (compile-time), 32 amps.
template<int M>
__device__ __forceinline__ void apply1q(float2* st, float2 g00, float2 g01,
                                        float2 g10, float2 g11) {
#pragma unroll
    for (int j = 0; j < 32; ++j) {
        if (j & M) continue;
        float2 a = st[j], b = st[j + M];
        float2 na = pk_cmul(g00, a); na = pk_cmac(na, g01, b);
        float2 nb = pk_cmul(g10, a); nb = pk_cmac(nb, g11, b);
        st[j] = na; st[j + M] = nb;
    }
}

// Local CNOT: pure register renaming after unroll.
template<int MC, int MT>
__device__ __forceinline__ void cnot(float2* st) {
#pragma unroll
    for (int j = 0; j < 32; ++j) {
        if ((j & MC) && !(j & MT)) {
            float2 tmp = st[j]; st[j] = st[j + MT]; st[j + MT] = tmp;
        }
    }
}

struct cf { float r, i; };
__device__ __forceinline__ cf scmul(cf a, cf b) {
    return { fmaf(a.r, b.r, -a.i * b.i), fmaf(a.r, b.i, a.i * b.r) };
}

__global__ __launch_bounds__(256, 2) void qsim_kernel(
    const float* __restrict__ x, const float* __restrict__ theta,
    float* __restrict__ out) {
    // ---- per-block: build the 18 fused RZ*RY*RX gate matrices into LDS ----
    __shared__ float2 gs[18 * 4];
    const int t = threadIdx.x;
    if (t < 18) {
        const float* th = theta + t * 3;   // theta[l][q][0..2], t = l*6+q
        float sx, cx, sy, cy, sz, cz;
        __sincosf(0.5f * th[0], &sx, &cx);
        __sincosf(0.5f * th[1], &sy, &cy);
        __sincosf(0.5f * th[2], &sz, &cz);
        // M = RY * RX
        cf m00 = {  cy * cx,  sy * sx };
        cf m01 = { -sy * cx, -cy * sx };
        cf m10 = {  sy * cx, -cy * sx };
        cf m11 = {  cy * cx, -sy * sx };
        // G = RZ * M : row0 *= e^{-i th2/2}, row1 *= e^{+i th2/2}
        cf e0 = { cz, -sz }, e1 = { cz, sz };
        cf g00 = scmul(e0, m00), g01 = scmul(e0, m01);
        cf g10 = scmul(e1, m10), g11 = scmul(e1, m11);
        float2* o = gs + t * 4;
        o[0] = make_float2(g00.r, g00.i);
        o[1] = make_float2(g01.r, g01.i);
        o[2] = make_float2(g10.r, g10.i);
        o[3] = make_float2(g11.r, g11.i);
    }
    __syncthreads();

    const int tg = blockIdx.x * 256 + t;
    const int b  = tg >> 1;            // batch element
    const bool pb = (tg & 1) != 0;     // this lane's value of global bit5 (q0)

    // ---- encoding: angles from x, tensor-product initial half-state ----
    const float4* xv = reinterpret_cast<const float4*>(x + (size_t)b * 24);

    float2 st[32];
#pragma unroll
    for (int q = 0; q < 6; ++q) {
        float4 v = xv[q];
        float m = (v.x + v.y + v.z + v.w) * 0.25f;
        m = fminf(fmaxf(m, -6.0f), 6.0f);
        float a = m * 0.52359877559829887308f;   // pi/6
        float s2, c2, s4, c4;
        __sincosf(0.50f * a, &s2, &c2);
        __sincosf(0.25f * a, &s4, &c4);
        // column of RZ(a/2)*RX(a) applied to |0>
        float2 v0 = make_float2(c4 * c2, -s4 * c2);
        float2 v1 = make_float2(s4 * s2, -c4 * s2);
        if (q == 0) {
            st[0] = pb ? v1 : v0;               // q0 component = lane parity
        } else {
            const int mq = 32 >> q;             // local masks 16,8,4,2,1
#pragma unroll
            for (int i = 0; i < 32; i += 2 * mq) {
                st[i + mq] = pk_cmul(st[i], v1);   // write high half first
                st[i]      = pk_cmul(st[i], v0);
            }
        }
    }

    // ---- 3 layers: CNOT ring + fused 1q gates (rolled: I-cache) ----
#pragma unroll 1
    for (int l = 0; l < 3; ++l) {
        // CNOT(0,1): control = bit5 = lane parity; p==1 swaps local j <-> j+16
#pragma unroll
        for (int j = 0; j < 16; ++j) {
            float2 lo = st[j], hi = st[j + 16];
            st[j].x      = pb ? hi.x : lo.x;  st[j].y      = pb ? hi.y : lo.y;
            st[j + 16].x = pb ? lo.x : hi.x;  st[j + 16].y = pb ? lo.y : hi.y;
        }
        cnot<16, 8>(st);   // CNOT(1,2)
        cnot< 8, 4>(st);   // CNOT(2,3)
        cnot< 4, 2>(st);   // CNOT(3,4)
        cnot< 2, 1>(st);   // CNOT(4,5)
        // CNOT(5,0): control = local bit0, target = bit5: cross-lane, odd j
#pragma unroll
        for (int j = 1; j < 32; j += 2) st[j] = xpair2(st[j]);

        const float2* g = gs + l * 24;

        // gate on q0 (split across the lane pair):
        // p=0: st[j] = g00*mine + g01*other ; p=1: st[j] = g11*mine + g10*other
        {
            float2 q00 = g[0], q01 = g[1], q10 = g[2], q11 = g[3];
            float2 gm, go;
            gm.x = pb ? q11.x : q00.x;  gm.y = pb ? q11.y : q00.y;
            go.x = pb ? q10.x : q01.x;  go.y = pb ? q10.y : q01.y;
#pragma unroll
            for (int j = 0; j < 32; ++j) {
                float2 other = xpair2(st[j]);     // lockstep pre-update read
                float2 nv = pk_cmul(gm, st[j]);
                st[j] = pk_cmac(nv, go, other);
            }
        }
        // local gates q1..q5
        apply1q<16>(st, g[ 4], g[ 5], g[ 6], g[ 7]);
        apply1q< 8>(st, g[ 8], g[ 9], g[10], g[11]);
        apply1q< 4>(st, g[12], g[13], g[14], g[15]);
        apply1q< 2>(st, g[16], g[17], g[18], g[19]);
        apply1q< 1>(st, g[20], g[21], g[22], g[23]);
    }

    // ---- measurements ----
    // local bits: bit4=q1, bit3=q2, bit2=q3, bit1=q4, bit0=q5
    // Z0 sign = lane parity; Z2 sign = local bit3; Z4 sign = local bit1
    float2 ps[4];
#pragma unroll
    for (int k = 0; k < 4; ++k) ps[k] = make_float2(0.f, 0.f);
#pragma unroll
    for (int j = 0; j < 32; ++j) {
        const int gi = (((j >> 3) & 1) << 1) | ((j >> 1) & 1);
        ps[gi] = pk_sqacc(ps[gi], st[j]);
    }
    float s[4];
#pragma unroll
    for (int k = 0; k < 4; ++k) s[k] = ps[k].x + ps[k].y;
    float tot = (s[0] + s[1]) + (s[2] + s[3]);
    float z0 = pb ? -tot : tot;
    float z2 = (s[0] + s[1]) - (s[2] + s[3]);
    float z4 = (s[0] + s[2]) - (s[1] + s[3]);

    float2 xa = make_float2(0.f, 0.f), xb = xa, xc = xa;
#pragma unroll
    for (int j = 0; j < 32; ++j) {
        if (!(j & 16)) xa = pk_macv(xa, st[j], st[j + 16]);
        if (!(j &  4)) xb = pk_macv(xb, st[j], st[j +  4]);
        if (!(j &  1)) xc = pk_macv(xc, st[j], st[j +  1]);
    }
    float x1 = xa.x + xa.y;
    float x3 = xb.x + xb.y;
    float x5 = xc.x + xc.y;

    // combine the two half-state partials of each element
    z0 += xpair(z0); z2 += xpair(z2); z4 += xpair(z4);
    x1 += xpair(x1); x3 += xpair(x3); x5 += xpair(x5);
    x1 *= 2.f; x3 *= 2.f; x5 *= 2.f;

    // out[b] = {z0, x1, z2, x3, z4, x5, z0, x1}; lane p writes float4 #p
    float oa = pb ? z4 : z0;
    float ob = pb ? x5 : x1;
    float oc = pb ? z0 : z2;
    float od = pb ? x1 : x3;
    float4* ov = reinterpret_cast<float4*>(out + (size_t)b * 8);
    ov[pb ? 1 : 0] = make_float4(oa, ob, oc, od);
}

extern "C" void kernel_launch(void* const* d_in, const int* in_sizes, int n_in,
                              void* d_out, int out_size, void* d_ws, size_t ws_size,
                              hipStream_t stream) {
    const float* x     = (const float*)d_in[0];   // [B, 24] f32
    const float* theta = (const float*)d_in[1];   // [3, 6, 3] f32
    float* out = (float*)d_out;                   // [B, 8] f32
    const int B = in_sizes[0] / 24;               // 131072
    qsim_kernel<<<dim3((B * 2) / 256), dim3(256), 0, stream>>>(x, theta, out);
}